// Round 4
// baseline (12020.101 us; speedup 1.0000x reference)
//
#include <hip/hip_runtime.h>
#include <math.h>

#define NSTATES 1024
#define TT      4096
#define DD      20

#define FW_BLOCKS  64
#define FW_THREADS 256
#define JPB  16      // j per block   (FW_BLOCKS * JPB = NSTATES)
#define NSEG 16      // k segments    (JPB * NSEG = FW_THREADS)
#define KSEG 64      // k per segment (NSEG * KSEG = NSTATES)

#define SENT 0x7FC00000u   // canonical NaN: computed column values are never NaN

// workspace layout (bytes)
#define OFF_LAT   ((size_t)0)               // 4 MB  logA transposed: lat[j*N+k] = log(trans[k][j])
#define OFF_E     ((size_t)4 << 20)         // 16 MB emissions E[t*N+n]
#define OFF_COLS  ((size_t)20 << 20)        // 16 MB per-step columns cols[t*N+j]
#define OFF_PTR   ((size_t)36 << 20)        // 8 MB  u16 backpointers, rows 1..T-1

typedef unsigned int u32;

#define ALD(p) __hip_atomic_load((p), __ATOMIC_RELAXED, __HIP_MEMORY_SCOPE_AGENT)

__global__ void k_init(uint4* __restrict__ cols4) {
    // fill 16 MB of cols with the sentinel (4M words = 1M uint4)
    int id = blockIdx.x * 256 + threadIdx.x;
    cols4[id] = make_uint4(SENT, SENT, SENT, SENT);
}

__global__ void k_logtrans(const float* __restrict__ tr, float* __restrict__ lat) {
    int id = blockIdx.x * 256 + threadIdx.x;        // 1M threads
    int k = id >> 10, j = id & 1023;
    lat[(size_t)j * NSTATES + k] = logf(tr[id]);    // coalesced read, strided write (one-time)
}

__global__ void k_emis(const float* __restrict__ ev, const float* __restrict__ epar,
                       const float* __restrict__ prior, float* __restrict__ E,
                       float* __restrict__ cols) {
    int n = blockIdx.x * 256 + threadIdx.x;         // 4 x 256 = 1024
    int t = blockIdx.y;                             // 0..4095
    const float* ep = epar + (size_t)n * (2 * DD);
    const float* x  = ev + (size_t)t * DD;
    float acc = 0.0f;
    #pragma unroll
    for (int d = 0; d < DD; ++d) {
        float m = ep[2 * d];
        float s = ep[2 * d + 1];
        // faithful to reference: p = (2*pi*s)^(-0.5) * exp(-(x-m)^2/(2*s^2)); logp = log(p)
        float tp   = 6.2831853071795864769f * s;
        float coef = 1.0f / sqrtf(tp);
        float df   = x[d] - m;
        float num  = df * df;
        float den  = 2.0f * (s * s);
        float p    = coef * expf(-num / den);
        acc += logf(p);                             // -inf propagates; values are never NaN
    }
    E[(size_t)t * NSTATES + n] = acc;
    if (t == 0) cols[n] = logf(prior[n]) + acc;     // col0 = log(prior) + logp0 (overwrites sentinel)
}

// Forward pass. Round-3 structure (proven) with ONE change: the poll is now a
// sleepless two-sweep pipelined poll. One 4-word sweep is always in flight
// while the previous sweep is checked, so the re-check cadence is the loop
// body (~tens of cycles) instead of RTT+sleep (~1000 cycles). This collapses
// the max-over-16K-pollers detection tail that round 3 showed dominates the
// step period (intra-block compute removal bought only ~36 cy/step).
__global__ __launch_bounds__(FW_THREADS, 1) void k_forward(
    const float* __restrict__ lat, const float* __restrict__ E,
    float* __restrict__ cols, unsigned short* __restrict__ bptr)
{
    // padded [16][68]: row r holds words [r*64, r*64+64) of the prev column.
    __shared__ __align__(16) float prevs[NSEG * 68];
    __shared__ float          smaxw[4][JPB];   // per-wave partials (segs 4w..4w+3)
    __shared__ unsigned short sidxw[4][JPB];
    const int tid  = threadIdx.x;
    const int seg  = tid >> 4;                  // 0..15: k in [seg*64, seg*64+64)
    const int jj   = tid & (JPB - 1);
    const int wav  = tid >> 6;                  // wave id 0..3 (holds segs 4w..4w+3)
    const int j0   = blockIdx.x * JPB;
    const int j    = j0 + jj;
    const float lat00 = lat[0];                 // log trans[0][0], for the j==0 quirk

    // preload this thread's lat slice into registers (loop-invariant, 64 VGPRs)
    float4 latr[16];
    {
        const float* lrow = lat + (size_t)j * NSTATES + seg * KSEG;
        #pragma unroll
        for (int u = 0; u < 16; ++u) latr[u] = *(const float4*)(lrow + u * 4);
    }

    // thread stages its 4 polled words at padded (row tid>>4, col (tid&15)*4)
    float* dstp = &prevs[(tid >> 4) * 68 + (tid & 15) * 4];
    const float* rowp = &prevs[seg * 68];

    for (int t = 1; t < TT; ++t) {
        // E prefetch: issued before the poll; drains under the poll's waits.
        float e = E[(size_t)t * NSTATES + j];

        // ---- pipelined sleepless poll of this thread's 4 words.
        // Invariant: when checking sweep X, sweep Y is already in flight, so
        // the compiler's counted vmcnt waits only for X; a fresh sweep is
        // re-issued immediately after each failed check.
        const u32* p = (const u32*)(cols + (size_t)(t - 1) * NSTATES) + tid * 4;
        u32 w0, w1, w2, w3;
        {
            u32 a0 = ALD(p + 0), a1 = ALD(p + 1), a2 = ALD(p + 2), a3 = ALD(p + 3);
            for (;;) {
                u32 b0 = ALD(p + 0), b1 = ALD(p + 1), b2 = ALD(p + 2), b3 = ALD(p + 3);
                if (a0 != SENT && a1 != SENT && a2 != SENT && a3 != SENT) {
                    w0 = a0; w1 = a1; w2 = a2; w3 = a3; break;
                }
                a0 = ALD(p + 0); a1 = ALD(p + 1); a2 = ALD(p + 2); a3 = ALD(p + 3);
                if (b0 != SENT && b1 != SENT && b2 != SENT && b3 != SENT) {
                    w0 = b0; w1 = b1; w2 = b2; w3 = b3; break;
                }
            }
        }
        {
            float4 v;
            v.x = __uint_as_float(w0);
            v.y = __uint_as_float(w1);
            v.z = __uint_as_float(w2);
            v.w = __uint_as_float(w3);
            *(float4*)dstp = v;                 // padded b128 store, conflict-free
        }
        __syncthreads();                        // barrier 1: staging visible to all

        // ---- scan this thread's 64 k's for its j: first-max (strict >, asc k)
        float best = -__builtin_inff();
        int bidx = seg * KSEG;
        #pragma unroll
        for (int u = 0; u < 16; ++u) {
            float4 q  = *(const float4*)(rowp + u * 4);   // 16-lane broadcast
            float4 wv = latr[u];
            int k0 = seg * KSEG + u * 4;
            float v0 = q.x + wv.x;
            float v1 = q.y + wv.y;
            float v2 = q.z + wv.z;
            float v3 = q.w + wv.w;
            if (v0 > best) { best = v0; bidx = k0;     }
            if (v1 > best) { best = v1; bidx = k0 + 1; }
            if (v2 > best) { best = v2; bidx = k0 + 2; }
            if (v3 > best) { best = v3; bidx = k0 + 3; }
        }

        // ---- combine the wave's 4 segs per j via shfl (disjoint ascending k
        // ranges: tie -> smaller bidx == sequential first-max). No sync.
        {
            float ov = __shfl_xor(best, 16);
            int   oi = __shfl_xor(bidx, 16);
            if (ov > best || (ov == best && oi < bidx)) { best = ov; bidx = oi; }
            ov = __shfl_xor(best, 32);
            oi = __shfl_xor(bidx, 32);
            if (ov > best || (ov == best && oi < bidx)) { best = ov; bidx = oi; }
        }
        if ((tid & 63) < JPB) {                 // one lane per (wave, jj)
            smaxw[wav][jj] = best;
            sidxw[wav][jj] = (unsigned short)bidx;
        }
        __syncthreads();                        // barrier 2: partials visible

        // ---- final 4-deep combine (ascending wave == ascending seg) + publish
        if (tid < JPB) {
            float m = smaxw[0][tid];
            int  mi = sidxw[0][tid];
            #pragma unroll
            for (int ww = 1; ww < 4; ++ww) {
                float v = smaxw[ww][tid];
                if (v > m) { m = v; mi = sidxw[ww][tid]; }
            }
            int jw = j0 + tid;
            // reference quirk: j==0 forced from state 0; prevs[0] (staged by
            // tid 0, wave 0 -- not yet overwritten) is cols[t-1][0].
            float val = (jw == 0) ? (prevs[0] + lat00) : m;
            float out = val + e;                // e: jj == tid for tid < 16
            __hip_atomic_store((u32*)(cols + (size_t)t * NSTATES) + jw,
                               __float_as_uint(out), __ATOMIC_RELAXED,
                               __HIP_MEMORY_SCOPE_AGENT);
            bptr[(size_t)t * NSTATES + jw] = (unsigned short)mi;
        }
        // no third barrier: next iteration's staging only overwrites prevs rows
        // whose readers (scans) completed before barrier 2; smaxw reuse is
        // ordered by the next iteration's barrier 1.
    }
}

#define BTC 24  // ptr rows per LDS chunk (48 KB)
__global__ void k_backtrace(const float* __restrict__ lastcol,
                            const unsigned short* __restrict__ bptr,
                            int* __restrict__ seq)
{
    __shared__ unsigned short ring[BTC][NSTATES];
    __shared__ int s_front;
    const int lane = threadIdx.x;   // 64 threads = 1 wave

    // last = first-max argmax over final column
    float best = -__builtin_inff();
    int bi = 0;
    for (int n2 = lane; n2 < NSTATES; n2 += 64) {
        float v = lastcol[n2];
        if (v > best) { best = v; bi = n2; }
    }
    #pragma unroll
    for (int off = 32; off > 0; off >>= 1) {
        float ov = __shfl_xor(best, off);
        int   oi = __shfl_xor(bi, off);
        if (ov > best || (ov == best && oi < bi)) { best = ov; bi = oi; }
    }
    if (lane == 0) { seq[TT] = bi; seq[TT - 1] = bi; s_front = bi; }
    __syncthreads();

    // chase rows r = T-1 .. 1 (seq[r-1] = ptr[r][front]) in descending LDS chunks
    for (int rhi = TT - 1; rhi >= 1; rhi -= BTC) {
        int rlo = rhi - (BTC - 1);
        if (rlo < 1) rlo = 1;
        for (int rr = rlo; rr <= rhi; ++rr) {
            const uint4* src = (const uint4*)(bptr + (size_t)rr * NSTATES);
            uint4* dst = (uint4*)(&ring[rr - rlo][0]);
            dst[lane]      = src[lane];
            dst[lane + 64] = src[lane + 64];
        }
        __syncthreads();
        if (lane == 0) {
            int front = s_front;
            for (int r = rhi; r >= rlo; --r) {
                front = (int)ring[r - rlo][front];
                seq[r - 1] = front;
            }
            s_front = front;
        }
        __syncthreads();
    }
}

extern "C" void kernel_launch(void* const* d_in, const int* in_sizes, int n_in,
                              void* d_out, int out_size, void* d_ws, size_t ws_size,
                              hipStream_t stream) {
    const float* ev    = (const float*)d_in[0];   // [T, D]
    const float* prior = (const float*)d_in[1];   // [N]
    const float* tr    = (const float*)d_in[2];   // [N, N]
    const float* epar  = (const float*)d_in[3];   // [N, D, 2]
    int* seq = (int*)d_out;                       // [T+1]
    char* ws = (char*)d_ws;
    float* lat  = (float*)(ws + OFF_LAT);
    float* E    = (float*)(ws + OFF_E);
    float* cols = (float*)(ws + OFF_COLS);
    unsigned short* bptr = (unsigned short*)(ws + OFF_PTR);

    k_init<<<4096, 256, 0, stream>>>((uint4*)cols);              // sentinel-fill 16 MB
    k_logtrans<<<4096, 256, 0, stream>>>(tr, lat);
    k_emis<<<dim3(4, TT), 256, 0, stream>>>(ev, epar, prior, E, cols);
    k_forward<<<FW_BLOCKS, FW_THREADS, 0, stream>>>(lat, E, cols, bptr);
    k_backtrace<<<1, 64, 0, stream>>>(cols + (size_t)(TT - 1) * NSTATES, bptr, seq);
}

// Round 5
// 11685.909 us; speedup vs baseline: 1.0286x; 1.0286x over previous
//
#include <hip/hip_runtime.h>
#include <math.h>

#define NSTATES 1024
#define TT      4096
#define DD      20

#define FW_BLOCKS  64
#define FW_THREADS 256
#define JPB  16      // j per block   (FW_BLOCKS * JPB = NSTATES)
#define NSEG 16      // k segments    (JPB * NSEG = FW_THREADS)
#define KSEG 64      // k per segment (NSEG * KSEG = NSTATES)

#define SENT 0x7FC00000u   // canonical NaN: computed column values are never NaN

// workspace layout (bytes)
#define OFF_LAT   ((size_t)0)               // 4 MB  logA transposed: lat[j*N+k] = log(trans[k][j])
#define OFF_E     ((size_t)4 << 20)         // 16 MB emissions E[t*N+n]
#define OFF_COLS  ((size_t)20 << 20)        // 16 MB per-step columns cols[t*N+j]
#define OFF_PTR   ((size_t)36 << 20)        // 8 MB  u16 backpointers, rows 1..T-1

typedef unsigned int u32;
typedef u32 u32x4 __attribute__((ext_vector_type(4)));

#define ALD(p) __hip_atomic_load((p), __ATOMIC_RELAXED, __HIP_MEMORY_SCOPE_AGENT)

__global__ void k_init(uint4* __restrict__ cols4) {
    // fill 16 MB of cols with the sentinel (4M words = 1M uint4)
    int id = blockIdx.x * 256 + threadIdx.x;
    cols4[id] = make_uint4(SENT, SENT, SENT, SENT);
}

__global__ void k_logtrans(const float* __restrict__ tr, float* __restrict__ lat) {
    int id = blockIdx.x * 256 + threadIdx.x;        // 1M threads
    int k = id >> 10, j = id & 1023;
    lat[(size_t)j * NSTATES + k] = logf(tr[id]);    // coalesced read, strided write (one-time)
}

__global__ void k_emis(const float* __restrict__ ev, const float* __restrict__ epar,
                       const float* __restrict__ prior, float* __restrict__ E,
                       float* __restrict__ cols) {
    int n = blockIdx.x * 256 + threadIdx.x;         // 4 x 256 = 1024
    int t = blockIdx.y;                             // 0..4095
    const float* ep = epar + (size_t)n * (2 * DD);
    const float* x  = ev + (size_t)t * DD;
    float acc = 0.0f;
    #pragma unroll
    for (int d = 0; d < DD; ++d) {
        float m = ep[2 * d];
        float s = ep[2 * d + 1];
        // faithful to reference: p = (2*pi*s)^(-0.5) * exp(-(x-m)^2/(2*s^2)); logp = log(p)
        float tp   = 6.2831853071795864769f * s;
        float coef = 1.0f / sqrtf(tp);
        float df   = x[d] - m;
        float num  = df * df;
        float den  = 2.0f * (s * s);
        float p    = coef * expf(-num / den);
        acc += logf(p);                             // -inf propagates; values are never NaN
    }
    E[(size_t)t * NSTATES + n] = acc;
    if (t == 0) cols[n] = logf(prior[n]) + acc;     // col0 = log(prior) + logp0 (overwrites sentinel)
}

// Forward pass. Round-3 structure (proven best) with ONE change: the poll is
// done by wave 0 only, using wide device-scope loads.
//   - 4 x global_load_dwordx4 sc1 per lane covers the full 1024-word column
//     per sweep with 64 line-requests/block (vs 256) -> 4x poll-traffic cut,
//     attacking the contention that round 4 proved inflates the handoff RTT.
//   - detection is wave-synchronous: one wave checks the whole column at once,
//     collapsing the per-thread sleep-phase spread (max over 256 threads).
//   - insurance: every 16 failed wide sweeps, one atomic-load sweep (the
//     proven-coherent primitive) may satisfy the exit -> hang-impossible even
//     if sc1 wide loads were stale; in steady state it never triggers.
// Waves 1-3 park at barrier 1 during the poll (free) and scan as before.
__global__ __launch_bounds__(FW_THREADS, 1) void k_forward(
    const float* __restrict__ lat, const float* __restrict__ E,
    float* __restrict__ cols, unsigned short* __restrict__ bptr)
{
    // padded [16][68]: row r holds words [r*64, r*64+64) of the prev column.
    __shared__ __align__(16) float prevs[NSEG * 68];
    __shared__ float          smaxw[4][JPB];   // per-wave partials (segs 4w..4w+3)
    __shared__ unsigned short sidxw[4][JPB];
    const int tid  = threadIdx.x;
    const int seg  = tid >> 4;                  // 0..15: k in [seg*64, seg*64+64)
    const int jj   = tid & (JPB - 1);
    const int wav  = tid >> 6;                  // wave id 0..3 (holds segs 4w..4w+3)
    const int j0   = blockIdx.x * JPB;
    const int j    = j0 + jj;
    const float lat00 = lat[0];                 // log trans[0][0], for the j==0 quirk

    // preload this thread's lat slice into registers (loop-invariant, 64 VGPRs)
    float4 latr[16];
    {
        const float* lrow = lat + (size_t)j * NSTATES + seg * KSEG;
        #pragma unroll
        for (int u = 0; u < 16; ++u) latr[u] = *(const float4*)(lrow + u * 4);
    }

    const float* rowp = &prevs[seg * 68];

    for (int t = 1; t < TT; ++t) {
        // E prefetch: issued before poll/barrier; drains under the wait.
        float e = E[(size_t)t * NSTATES + j];

        if (tid < 64) {
            // ---- wave-0 poll of the full previous column.
            // lane l covers words {q*256 + 4l .. +3}, q = 0..3: each dwordx4
            // is lane-contiguous (64 lanes x 16B = 1024B = 16 lines).
            const u32* pw = (const u32*)(cols + (size_t)(t - 1) * NSTATES) + 4 * tid;
            u32x4 A, B, C, D2;
            int tries = 0;
            for (;;) {
                asm volatile(
                    "global_load_dwordx4 %0, %4, off sc1\n\t"
                    "global_load_dwordx4 %1, %4, off offset:1024 sc1\n\t"
                    "global_load_dwordx4 %2, %4, off offset:2048 sc1\n\t"
                    "global_load_dwordx4 %3, %4, off offset:3072 sc1\n\t"
                    "s_waitcnt vmcnt(0)"
                    : "=&v"(A), "=&v"(B), "=&v"(C), "=&v"(D2)
                    : "v"(pw)
                    : "memory");
                bool ok = (A.x != SENT) & (A.y != SENT) & (A.z != SENT) & (A.w != SENT)
                        & (B.x != SENT) & (B.y != SENT) & (B.z != SENT) & (B.w != SENT)
                        & (C.x != SENT) & (C.y != SENT) & (C.z != SENT) & (C.w != SENT)
                        & (D2.x != SENT) & (D2.y != SENT) & (D2.z != SENT) & (D2.w != SENT);
                if (ok) break;
                if (++tries >= 16) {
                    // coherence insurance: proven atomic-load sweep
                    u32 s0[16];
                    bool ok2 = true;
                    #pragma unroll
                    for (int q = 0; q < 4; ++q) {
                        #pragma unroll
                        for (int i = 0; i < 4; ++i) {
                            u32 v = ALD(pw + q * 256 + i);
                            s0[q * 4 + i] = v;
                            ok2 &= (v != SENT);
                        }
                    }
                    if (ok2) {
                        A = (u32x4){s0[0], s0[1], s0[2], s0[3]};
                        B = (u32x4){s0[4], s0[5], s0[6], s0[7]};
                        C = (u32x4){s0[8], s0[9], s0[10], s0[11]};
                        D2 = (u32x4){s0[12], s0[13], s0[14], s0[15]};
                        break;
                    }
                    tries = 0;
                }
                __builtin_amdgcn_s_sleep(1);
            }
            // ---- stage: quarter q -> padded row q*4 + (l>>4), col (l&15)*4
            float* st = &prevs[(tid >> 4) * 68 + (tid & 15) * 4];
            *(u32x4*)(st + 0 * 272) = A;     // 272 = 4 rows * 68 floats
            *(u32x4*)(st + 1 * 272) = B;
            *(u32x4*)(st + 2 * 272) = C;
            *(u32x4*)(st + 3 * 272) = D2;
        }
        __syncthreads();                        // barrier 1: staging visible to all

        // ---- scan this thread's 64 k's for its j: first-max (strict >, asc k)
        float best = -__builtin_inff();
        int bidx = seg * KSEG;
        #pragma unroll
        for (int u = 0; u < 16; ++u) {
            float4 q  = *(const float4*)(rowp + u * 4);   // 16-lane broadcast
            float4 wv = latr[u];
            int k0 = seg * KSEG + u * 4;
            float v0 = q.x + wv.x;
            float v1 = q.y + wv.y;
            float v2 = q.z + wv.z;
            float v3 = q.w + wv.w;
            if (v0 > best) { best = v0; bidx = k0;     }
            if (v1 > best) { best = v1; bidx = k0 + 1; }
            if (v2 > best) { best = v2; bidx = k0 + 2; }
            if (v3 > best) { best = v3; bidx = k0 + 3; }
        }

        // ---- combine the wave's 4 segs per j via shfl (disjoint ascending k
        // ranges: tie -> smaller bidx == sequential first-max). No sync.
        {
            float ov = __shfl_xor(best, 16);
            int   oi = __shfl_xor(bidx, 16);
            if (ov > best || (ov == best && oi < bidx)) { best = ov; bidx = oi; }
            ov = __shfl_xor(best, 32);
            oi = __shfl_xor(bidx, 32);
            if (ov > best || (ov == best && oi < bidx)) { best = ov; bidx = oi; }
        }
        if ((tid & 63) < JPB) {                 // one lane per (wave, jj)
            smaxw[wav][jj] = best;
            sidxw[wav][jj] = (unsigned short)bidx;
        }
        __syncthreads();                        // barrier 2: partials visible

        // ---- final 4-deep combine (ascending wave == ascending seg) + publish
        if (tid < JPB) {
            float m = smaxw[0][tid];
            int  mi = sidxw[0][tid];
            #pragma unroll
            for (int ww = 1; ww < 4; ++ww) {
                float v = smaxw[ww][tid];
                if (v > m) { m = v; mi = sidxw[ww][tid]; }
            }
            int jw = j0 + tid;
            // reference quirk: j==0 forced from state 0; prevs[0] (staged by
            // wave-0 lane 0, quarter 0 -- not yet overwritten) is cols[t-1][0].
            float val = (jw == 0) ? (prevs[0] + lat00) : m;
            float out = val + e;                // e: jj == tid for tid < 16
            __hip_atomic_store((u32*)(cols + (size_t)t * NSTATES) + jw,
                               __float_as_uint(out), __ATOMIC_RELAXED,
                               __HIP_MEMORY_SCOPE_AGENT);
            bptr[(size_t)t * NSTATES + jw] = (unsigned short)mi;
        }
        // no third barrier: prevs is rewritten only by wave 0 at t+1, after it
        // passes barrier 2 (all prevs readers done); waves 1-3 park at barrier
        // 1 of t+1 while wave 0 stages; smaxw reuse is ordered by barrier 1.
    }
}

#define BTC 24  // ptr rows per LDS chunk (48 KB)
__global__ void k_backtrace(const float* __restrict__ lastcol,
                            const unsigned short* __restrict__ bptr,
                            int* __restrict__ seq)
{
    __shared__ unsigned short ring[BTC][NSTATES];
    __shared__ int s_front;
    const int lane = threadIdx.x;   // 64 threads = 1 wave

    // last = first-max argmax over final column
    float best = -__builtin_inff();
    int bi = 0;
    for (int n2 = lane; n2 < NSTATES; n2 += 64) {
        float v = lastcol[n2];
        if (v > best) { best = v; bi = n2; }
    }
    #pragma unroll
    for (int off = 32; off > 0; off >>= 1) {
        float ov = __shfl_xor(best, off);
        int   oi = __shfl_xor(bi, off);
        if (ov > best || (ov == best && oi < bi)) { best = ov; bi = oi; }
    }
    if (lane == 0) { seq[TT] = bi; seq[TT - 1] = bi; s_front = bi; }
    __syncthreads();

    // chase rows r = T-1 .. 1 (seq[r-1] = ptr[r][front]) in descending LDS chunks
    for (int rhi = TT - 1; rhi >= 1; rhi -= BTC) {
        int rlo = rhi - (BTC - 1);
        if (rlo < 1) rlo = 1;
        for (int rr = rlo; rr <= rhi; ++rr) {
            const uint4* src = (const uint4*)(bptr + (size_t)rr * NSTATES);
            uint4* dst = (uint4*)(&ring[rr - rlo][0]);
            dst[lane]      = src[lane];
            dst[lane + 64] = src[lane + 64];
        }
        __syncthreads();
        if (lane == 0) {
            int front = s_front;
            for (int r = rhi; r >= rlo; --r) {
                front = (int)ring[r - rlo][front];
                seq[r - 1] = front;
            }
            s_front = front;
        }
        __syncthreads();
    }
}

extern "C" void kernel_launch(void* const* d_in, const int* in_sizes, int n_in,
                              void* d_out, int out_size, void* d_ws, size_t ws_size,
                              hipStream_t stream) {
    const float* ev    = (const float*)d_in[0];   // [T, D]
    const float* prior = (const float*)d_in[1];   // [N]
    const float* tr    = (const float*)d_in[2];   // [N, N]
    const float* epar  = (const float*)d_in[3];   // [N, D, 2]
    int* seq = (int*)d_out;                       // [T+1]
    char* ws = (char*)d_ws;
    float* lat  = (float*)(ws + OFF_LAT);
    float* E    = (float*)(ws + OFF_E);
    float* cols = (float*)(ws + OFF_COLS);
    unsigned short* bptr = (unsigned short*)(ws + OFF_PTR);

    k_init<<<4096, 256, 0, stream>>>((uint4*)cols);              // sentinel-fill 16 MB
    k_logtrans<<<4096, 256, 0, stream>>>(tr, lat);
    k_emis<<<dim3(4, TT), 256, 0, stream>>>(ev, epar, prior, E, cols);
    k_forward<<<FW_BLOCKS, FW_THREADS, 0, stream>>>(lat, E, cols, bptr);
    k_backtrace<<<1, 64, 0, stream>>>(cols + (size_t)(TT - 1) * NSTATES, bptr, seq);
}